// Round 7
// baseline (364.909 us; speedup 1.0000x reference)
//
#include <hip/hip_runtime.h>
#include <hip/hip_bf16.h>

// LSTM autoencoder: B=4096, T=128, F=32, H=64, 4H=256.
// ROUND 7: arithmetic restored BIT-IDENTICAL to round 3 (passed, absmax
// 9.293e7): plain sigmoid 1/(1+__expf(-z)), unscaled weights, bf16x3 split
// (hi+lo, 3 MFMAs). Rounds 5/6 proved the relu-LSTM is chaotic in its
// rounding-noise realization (bit-identical failures across different
// barrier codegen) — so arithmetic is frozen; only structure changes:
//  - grid 512, 8 batch rows/block (rows 8-15 of each MFMA tile duplicate
//    rows 0-7 via x-row clamp; row-independence keeps real rows bit-exact).
//    2 blocks/CU -> 2 waves/SIMD fill the issue slots that were 50% idle.
//  - fused-asm LDS-only barrier (s_waitcnt lgkmcnt(0)+s_barrier in ONE asm
//    with memory clobber): ordered at compile time, no vmcnt(0) drain so
//    the x prefetch / out stores stay in flight across steps.
//  - __launch_bounds__(256,2) caps VGPR at 256 so 2 blocks co-reside.

typedef __bf16 bf16x8 __attribute__((ext_vector_type(8)));
typedef float f32x4 __attribute__((ext_vector_type(4)));
typedef float f32x8 __attribute__((ext_vector_type(8)));

struct frag2 { bf16x8 hi, lo; };

__device__ __forceinline__ float sigmoidf_(float v) {
    return 1.0f / (1.0f + __expf(-v));
}

// LDS-only barrier: waitcnt+barrier fused in ONE asm (compiler memory fence
// both sides, no vmcnt drain)
__device__ __forceinline__ void hbar() {
    asm volatile("s_waitcnt lgkmcnt(0)\n\ts_barrier" ::: "memory");
}

__device__ __forceinline__ f32x4 mfma3(const frag2& a, const frag2& b, f32x4 c) {
    c = __builtin_amdgcn_mfma_f32_16x16x32_bf16(a.hi, b.hi, c, 0, 0, 0);
    c = __builtin_amdgcn_mfma_f32_16x16x32_bf16(a.lo, b.hi, c, 0, 0, 0);
    c = __builtin_amdgcn_mfma_f32_16x16x32_bf16(a.hi, b.lo, c, 0, 0, 0);
    return c;
}

// hi/lo B-fragment of a [K x LD] row-major fp32 matrix for mfma 16x16x32:
// lane l, elem e -> M[k0 + (l>>4)*8 + e][col]
template<int LD>
__device__ __forceinline__ frag2 load_fragB2(const float* __restrict__ M,
                                             int k0, int col, int lq) {
    frag2 r;
    const float* p = M + (size_t)(k0 + lq * 8) * LD + col;
#pragma unroll
    for (int e = 0; e < 8; ++e) {
        float v = p[(size_t)e * LD];
        __bf16 h = (__bf16)v;
        r.hi[e] = h;
        r.lo[e] = (__bf16)(v - (float)h);
    }
    return r;
}

__device__ __forceinline__ frag2 split_vec(f32x8 v) {
    frag2 r;
#pragma unroll
    for (int e = 0; e < 8; ++e) {
        __bf16 h = (__bf16)v[e];
        r.hi[e] = h;
        r.lo[e] = (__bf16)(v[e] - (float)h);
    }
    return r;
}

// swizzled byte offset inside one 16x64 bf16 h-tile (row = batch, 128B/row)
__device__ __forceinline__ int swz(int row, int byteoff) {
    return row * 128 + (byteoff ^ ((row & 7) << 4));
}

__global__ __launch_bounds__(256, 2)
void lstm_ae_kernel(const float* __restrict__ x,
                    const float* __restrict__ eW, const float* __restrict__ eU,
                    const float* __restrict__ eb,
                    const float* __restrict__ dW, const float* __restrict__ dU,
                    const float* __restrict__ db,
                    const float* __restrict__ nW, const float* __restrict__ nb,
                    float* __restrict__ out)
{
    const int tid = threadIdx.x;
    const int wv  = tid >> 6;        // wave 0..3
    const int ln  = tid & 63;
    const int l16 = ln & 15;
    const int lq  = ln >> 4;         // 0..3
    const int b0  = blockIdx.x << 3; // 8 REAL batch rows per block
    const int wcol = wv * 16 + l16;  // this wave's column within each gate

    // [buffer][hi/lo] planes of a 16x64 bf16 h-tile, XOR-swizzled
    // (rows 8-15 duplicate rows 0-7)
    __shared__ __align__(16) unsigned char hraw[2][2][2048];

    // loop-invariant LDS byte offsets for h exchange
    int offw[4];
#pragma unroll
    for (int r = 0; r < 4; ++r) offw[r] = swz(lq * 4 + r, wcol * 2);
    const int offr0 = swz(l16, lq * 16);
    const int offr1 = swz(l16, 64 + lq * 16);

    // ---------------- encoder weights (hi/lo register fragments) -------------
    frag2 W2[4], U2[4][2];
    float bz[4];
#pragma unroll
    for (int g = 0; g < 4; ++g) {
        W2[g]    = load_fragB2<256>(eW, 0,  g * 64 + wcol, lq);
        U2[g][0] = load_fragB2<256>(eU, 0,  g * 64 + wcol, lq);
        U2[g][1] = load_fragB2<256>(eU, 32, g * 64 + wcol, lq);
        bz[g]    = eb[g * 64 + wcol];
    }

    f32x4 cs = {0.f, 0.f, 0.f, 0.f};
    frag2 ha0, ha1;
#pragma unroll
    for (int e = 0; e < 8; ++e) {
        ha0.hi[e] = (__bf16)0.f; ha0.lo[e] = (__bf16)0.f;
        ha1.hi[e] = (__bf16)0.f; ha1.lo[e] = (__bf16)0.f;
    }

    // 2-deep x prefetch pipeline; pad rows (l16>=8) mirror rows 0-7 so the
    // duplicate trajectories stay valid (no OOB, no NaN)
    const float* xbase = x + (size_t)(b0 + (l16 & 7)) * (128 * 32) + lq * 8;
    f32x8 xv0 = *(const f32x8*)(xbase);
    f32x8 xv1 = *(const f32x8*)(xbase + 32);

    int q = 0;
    // ---------------- encoder scan ----------------
#pragma unroll 2
    for (int t = 0; t < 128; ++t) {
        const int tn = (t + 2 < 128) ? (t + 2) : 127;
        f32x8 xv2 = *(const f32x8*)(xbase + (size_t)tn * 32);

        frag2 xa2 = split_vec(xv0);

        f32x4 z[4];
#pragma unroll
        for (int g = 0; g < 4; ++g) {
            f32x4 zc = {bz[g], bz[g], bz[g], bz[g]};
            zc = mfma3(xa2, W2[g],    zc);
            zc = mfma3(ha0, U2[g][0], zc);
            zc = mfma3(ha1, U2[g][1], zc);
            z[g] = zc;
        }
#pragma unroll
        for (int r = 0; r < 4; ++r) {
            float ig = sigmoidf_(z[0][r]);
            float fg = sigmoidf_(z[1][r]);
            float gg = fmaxf(z[2][r], 0.f);
            float og = sigmoidf_(z[3][r]);
            cs[r] = fg * cs[r] + ig * gg;
            float hv = og * fmaxf(cs[r], 0.f);
            __bf16 hh = (__bf16)hv;
            __bf16 hl = (__bf16)(hv - (float)hh);
            *(__bf16*)(hraw[q][0] + offw[r]) = hh;
            *(__bf16*)(hraw[q][1] + offw[r]) = hl;
        }
        hbar();
        ha0.hi = *(const bf16x8*)(hraw[q][0] + offr0);
        ha0.lo = *(const bf16x8*)(hraw[q][1] + offr0);
        ha1.hi = *(const bf16x8*)(hraw[q][0] + offr1);
        ha1.lo = *(const bf16x8*)(hraw[q][1] + offr1);
        q ^= 1;
        xv0 = xv1; xv1 = xv2;
    }
    // ha0/ha1 now hold the encoded state (hi/lo A-fragments).

    // ------- decoder constant input projection zx = encoded@dW + db -------
    frag2 dU2[4][2];
    f32x4 zx[4];
#pragma unroll
    for (int g = 0; g < 4; ++g) {
        frag2 w0 = load_fragB2<256>(dW, 0,  g * 64 + wcol, lq);
        frag2 w1 = load_fragB2<256>(dW, 32, g * 64 + wcol, lq);
        dU2[g][0] = load_fragB2<256>(dU, 0,  g * 64 + wcol, lq);
        dU2[g][1] = load_fragB2<256>(dU, 32, g * 64 + wcol, lq);
        float bb = db[g * 64 + wcol];
        f32x4 zc = {bb, bb, bb, bb};
        zc = mfma3(ha0, w0, zc);
        zc = mfma3(ha1, w1, zc);
        zx[g] = zc;
    }
    // dense weights (waves 0,1: N-tiles of 16 over F=32)
    frag2 DN2[2];
    float ob = 0.f;
    if (wv < 2) {
        DN2[0] = load_fragB2<32>(nW, 0,  wv * 16 + l16, lq);
        DN2[1] = load_fragB2<32>(nW, 32, wv * 16 + l16, lq);
        ob     = nb[wv * 16 + l16];
    }

#pragma unroll
    for (int e = 0; e < 8; ++e) {
        ha0.hi[e] = (__bf16)0.f; ha0.lo[e] = (__bf16)0.f;
        ha1.hi[e] = (__bf16)0.f; ha1.lo[e] = (__bf16)0.f;
    }
    cs[0] = cs[1] = cs[2] = cs[3] = 0.f;
    q = 0;
    // ---------------- decoder scan + fused dense ----------------
#pragma unroll 2
    for (int t = 0; t < 128; ++t) {
        f32x4 z[4];
#pragma unroll
        for (int g = 0; g < 4; ++g) {
            f32x4 zc = zx[g];
            zc = mfma3(ha0, dU2[g][0], zc);
            zc = mfma3(ha1, dU2[g][1], zc);
            z[g] = zc;
        }
#pragma unroll
        for (int r = 0; r < 4; ++r) {
            float ig = sigmoidf_(z[0][r]);
            float fg = sigmoidf_(z[1][r]);
            float gg = fmaxf(z[2][r], 0.f);
            float og = sigmoidf_(z[3][r]);
            cs[r] = fg * cs[r] + ig * gg;
            float hv = og * fmaxf(cs[r], 0.f);
            __bf16 hh = (__bf16)hv;
            __bf16 hl = (__bf16)(hv - (float)hh);
            *(__bf16*)(hraw[q][0] + offw[r]) = hh;
            *(__bf16*)(hraw[q][1] + offw[r]) = hl;
        }
        hbar();
        ha0.hi = *(const bf16x8*)(hraw[q][0] + offr0);
        ha0.lo = *(const bf16x8*)(hraw[q][1] + offr0);
        ha1.hi = *(const bf16x8*)(hraw[q][0] + offr1);
        ha1.lo = *(const bf16x8*)(hraw[q][1] + offr1);
        // fused dense: out[b][t][:] = h_t @ nW + nb (real rows 0-7 only)
        if (wv < 2) {
            f32x4 oa = {ob, ob, ob, ob};
            oa = mfma3(ha0, DN2[0], oa);
            oa = mfma3(ha1, DN2[1], oa);
            if (lq < 2) {
#pragma unroll
                for (int r = 0; r < 4; ++r)
                    out[((size_t)(b0 + lq * 4 + r) * 128 + t) * 32 + wv * 16 + l16] = oa[r];
            }
        }
        q ^= 1;
    }
}

extern "C" void kernel_launch(void* const* d_in, const int* in_sizes, int n_in,
                              void* d_out, int out_size, void* d_ws, size_t ws_size,
                              hipStream_t stream) {
    const float* x  = (const float*)d_in[0];
    const float* eW = (const float*)d_in[1];
    const float* eU = (const float*)d_in[2];
    const float* eb = (const float*)d_in[3];
    const float* dW = (const float*)d_in[4];
    const float* dU = (const float*)d_in[5];
    const float* db = (const float*)d_in[6];
    const float* nW = (const float*)d_in[7];
    const float* nb = (const float*)d_in[8];
    float* out = (float*)d_out;

    hipLaunchKernelGGL(lstm_ae_kernel, dim3(4096 / 8), dim3(256), 0, stream,
                       x, eW, eU, eb, dW, dU, db, nW, nb, out);
}

// Round 9
// 244.240 us; speedup vs baseline: 1.4941x; 1.4941x over previous
//
#include <hip/hip_runtime.h>
#include <hip/hip_bf16.h>

// LSTM autoencoder: B=4096, T=128, F=32, H=64, 4H=256.
// One block per 16 batch rows (grid=256, 1 block/CU). 4 waves; wave w owns
// gate columns {i,f,g,o} x [16w,16w+16) so the cell update is pure per-lane.
//
// NUMERICS (round 9 = round 8 + compile fix): the relu-LSTM is chaotic — any
// ulp-level arithmetic change resamples the output error (r2-4: 9.3e7;
// r5-6: 1.03e9, bit-stable within each). The error scale is set by the
// largest per-step injection = the 2-plane/3-term split truncation (~2^-14
// rel). Fix: 3-plane bf16 split for h, x, U, W and 6-term products
// {11,12,21,22,13,31} -> injection ~2^-22, typical realization ~1e6 <<
// 1.15e8 threshold. Robust numerics unfreeze the arithmetic, so also:
// -log2e folded into i/f/o weights+bias, sigmoid = rcp(1+exp2(z)), and the
// fused-asm LDS-only barrier (validated round 7).

typedef __bf16 bf16x8 __attribute__((ext_vector_type(8)));
typedef float f32x4 __attribute__((ext_vector_type(4)));
typedef float f32x8 __attribute__((ext_vector_type(8)));

struct frag3 { bf16x8 p1, p2, p3; };
struct bf3 { __bf16 a, b, c; };

#define NEG_LOG2E (-1.44269504088896340736f)

// sigmoid(pre) where z = -log2e * pre came out of the scaled MFMA
__device__ __forceinline__ float fast_sig(float z) {
    return __builtin_amdgcn_rcpf(1.0f + __builtin_amdgcn_exp2f(z));
}

// LDS-only barrier: waitcnt+barrier fused in ONE asm (compiler memory fence
// both sides, no vmcnt drain -> x prefetch / out stores stay in flight)
__device__ __forceinline__ void hbar() {
    asm volatile("s_waitcnt lgkmcnt(0)\n\ts_barrier" ::: "memory");
}

// 6-term double-double-style MFMA product: keeps all cross terms >= 2^-24
__device__ __forceinline__ f32x4 mfma6(const frag3& a, const frag3& b, f32x4 c) {
    c = __builtin_amdgcn_mfma_f32_16x16x32_bf16(a.p1, b.p1, c, 0, 0, 0);
    c = __builtin_amdgcn_mfma_f32_16x16x32_bf16(a.p1, b.p2, c, 0, 0, 0);
    c = __builtin_amdgcn_mfma_f32_16x16x32_bf16(a.p2, b.p1, c, 0, 0, 0);
    c = __builtin_amdgcn_mfma_f32_16x16x32_bf16(a.p2, b.p2, c, 0, 0, 0);
    c = __builtin_amdgcn_mfma_f32_16x16x32_bf16(a.p1, b.p3, c, 0, 0, 0);
    c = __builtin_amdgcn_mfma_f32_16x16x32_bf16(a.p3, b.p1, c, 0, 0, 0);
    return c;
}

// 3-term product (output-stage only, error doesn't compound)
__device__ __forceinline__ f32x4 mfma3(const frag3& a, const frag3& b, f32x4 c) {
    c = __builtin_amdgcn_mfma_f32_16x16x32_bf16(a.p1, b.p1, c, 0, 0, 0);
    c = __builtin_amdgcn_mfma_f32_16x16x32_bf16(a.p1, b.p2, c, 0, 0, 0);
    c = __builtin_amdgcn_mfma_f32_16x16x32_bf16(a.p2, b.p1, c, 0, 0, 0);
    return c;
}

__device__ __forceinline__ bf3 split3(float v) {
    bf3 r;
    r.a = (__bf16)v;
    float r1 = v - (float)r.a;
    r.b = (__bf16)r1;
    r.c = (__bf16)(r1 - (float)r.b);
    return r;
}

// 3-plane B-fragment of a [K x LD] row-major fp32 matrix, scaled before split:
// lane l, elem e -> scale * M[k0 + (l>>4)*8 + e][col]
template<int LD>
__device__ __forceinline__ frag3 load_fragB3(const float* __restrict__ M,
                                             int k0, int col, int lq,
                                             float scale) {
    frag3 r;
    const float* p = M + (size_t)(k0 + lq * 8) * LD + col;
#pragma unroll
    for (int e = 0; e < 8; ++e) {
        bf3 s = split3(p[(size_t)e * LD] * scale);
        r.p1[e] = s.a; r.p2[e] = s.b; r.p3[e] = s.c;
    }
    return r;
}

__device__ __forceinline__ frag3 split3_vec(f32x8 v) {
    frag3 r;
#pragma unroll
    for (int e = 0; e < 8; ++e) {
        bf3 s = split3(v[e]);
        r.p1[e] = s.a; r.p2[e] = s.b; r.p3[e] = s.c;
    }
    return r;
}

// swizzled byte offset inside one 16x64 bf16 h-tile (row = batch, 128B/row)
__device__ __forceinline__ int swz(int row, int byteoff) {
    return row * 128 + (byteoff ^ ((row & 7) << 4));
}

__global__ __launch_bounds__(256, 1)
void lstm_ae_kernel(const float* __restrict__ x,
                    const float* __restrict__ eW, const float* __restrict__ eU,
                    const float* __restrict__ eb,
                    const float* __restrict__ dW, const float* __restrict__ dU,
                    const float* __restrict__ db,
                    const float* __restrict__ nW, const float* __restrict__ nb,
                    float* __restrict__ out)
{
    const int tid = threadIdx.x;
    const int wv  = tid >> 6;        // wave 0..3
    const int ln  = tid & 63;
    const int l16 = ln & 15;
    const int lq  = ln >> 4;         // 0..3
    const int b0  = blockIdx.x << 4; // 16 batch rows per block
    const int wcol = wv * 16 + l16;  // this wave's column within each gate

    // [buffer][plane1..3] of a 16x64 bf16 h-tile, XOR-swizzled
    __shared__ __align__(16) unsigned char hraw[2][3][2048];

    // loop-invariant LDS byte offsets for h exchange
    int offw[4];
#pragma unroll
    for (int r = 0; r < 4; ++r) offw[r] = swz(lq * 4 + r, wcol * 2);
    const int offr0 = swz(l16, lq * 16);
    const int offr1 = swz(l16, 64 + lq * 16);

    // gate scales: sigmoid gates get -log2e folded in; relu gate (g=2) doesn't
    const float gscale[4] = {NEG_LOG2E, NEG_LOG2E, 1.0f, NEG_LOG2E};

    // ---------------- encoder weights (3-plane register fragments) ----------
    frag3 W3[4], U3[4][2];
    float bz[4];
#pragma unroll
    for (int g = 0; g < 4; ++g) {
        W3[g]    = load_fragB3<256>(eW, 0,  g * 64 + wcol, lq, gscale[g]);
        U3[g][0] = load_fragB3<256>(eU, 0,  g * 64 + wcol, lq, gscale[g]);
        U3[g][1] = load_fragB3<256>(eU, 32, g * 64 + wcol, lq, gscale[g]);
        bz[g]    = eb[g * 64 + wcol] * gscale[g];
    }

    f32x4 cs = {0.f, 0.f, 0.f, 0.f};
    frag3 ha0, ha1;
#pragma unroll
    for (int e = 0; e < 8; ++e) {
        ha0.p1[e] = (__bf16)0.f; ha0.p2[e] = (__bf16)0.f; ha0.p3[e] = (__bf16)0.f;
        ha1.p1[e] = (__bf16)0.f; ha1.p2[e] = (__bf16)0.f; ha1.p3[e] = (__bf16)0.f;
    }

    // 2-deep x prefetch pipeline (barrier never drains vmcnt)
    const float* xbase = x + (size_t)(b0 + l16) * (128 * 32) + lq * 8;
    f32x8 xv0 = *(const f32x8*)(xbase);
    f32x8 xv1 = *(const f32x8*)(xbase + 32);

    int q = 0;
    // ---------------- encoder scan ----------------
#pragma unroll 2
    for (int t = 0; t < 128; ++t) {
        const int tn = (t + 2 < 128) ? (t + 2) : 127;
        f32x8 xv2 = *(const f32x8*)(xbase + (size_t)tn * 32);

        frag3 xa3 = split3_vec(xv0);

        f32x4 z[4];
#pragma unroll
        for (int g = 0; g < 4; ++g) {
            f32x4 zc = {bz[g], bz[g], bz[g], bz[g]};
            zc = mfma6(xa3, W3[g],    zc);
            zc = mfma6(ha0, U3[g][0], zc);
            zc = mfma6(ha1, U3[g][1], zc);
            z[g] = zc;
        }
#pragma unroll
        for (int r = 0; r < 4; ++r) {
            float ig = fast_sig(z[0][r]);
            float fg = fast_sig(z[1][r]);
            float gg = fmaxf(z[2][r], 0.f);
            float og = fast_sig(z[3][r]);
            cs[r] = fg * cs[r] + ig * gg;
            float hv = og * fmaxf(cs[r], 0.f);
            bf3 s = split3(hv);
            *(__bf16*)(hraw[q][0] + offw[r]) = s.a;
            *(__bf16*)(hraw[q][1] + offw[r]) = s.b;
            *(__bf16*)(hraw[q][2] + offw[r]) = s.c;
        }
        hbar();
        ha0.p1 = *(const bf16x8*)(hraw[q][0] + offr0);
        ha0.p2 = *(const bf16x8*)(hraw[q][1] + offr0);
        ha0.p3 = *(const bf16x8*)(hraw[q][2] + offr0);
        ha1.p1 = *(const bf16x8*)(hraw[q][0] + offr1);
        ha1.p2 = *(const bf16x8*)(hraw[q][1] + offr1);
        ha1.p3 = *(const bf16x8*)(hraw[q][2] + offr1);
        q ^= 1;
        xv0 = xv1; xv1 = xv2;
    }
    // ha0/ha1 now hold the encoded state (3-plane A-fragments).

    // ------- decoder constant input projection zx = encoded@dW + db -------
    frag3 dU3[4][2];
    f32x4 zx[4];
#pragma unroll
    for (int g = 0; g < 4; ++g) {
        frag3 w0 = load_fragB3<256>(dW, 0,  g * 64 + wcol, lq, gscale[g]);
        frag3 w1 = load_fragB3<256>(dW, 32, g * 64 + wcol, lq, gscale[g]);
        dU3[g][0] = load_fragB3<256>(dU, 0,  g * 64 + wcol, lq, gscale[g]);
        dU3[g][1] = load_fragB3<256>(dU, 32, g * 64 + wcol, lq, gscale[g]);
        float bb = db[g * 64 + wcol] * gscale[g];
        f32x4 zc = {bb, bb, bb, bb};
        zc = mfma6(ha0, w0, zc);
        zc = mfma6(ha1, w1, zc);
        zx[g] = zc;
    }
    // dense weights (waves 0,1: N-tiles of 16 over F=32); output stage ->
    // 3-term is plenty (no compounding)
    frag3 DN3[2];
    float ob = 0.f;
    if (wv < 2) {
        DN3[0] = load_fragB3<32>(nW, 0,  wv * 16 + l16, lq, 1.0f);
        DN3[1] = load_fragB3<32>(nW, 32, wv * 16 + l16, lq, 1.0f);
        ob     = nb[wv * 16 + l16];
    }

#pragma unroll
    for (int e = 0; e < 8; ++e) {
        ha0.p1[e] = (__bf16)0.f; ha0.p2[e] = (__bf16)0.f; ha0.p3[e] = (__bf16)0.f;
        ha1.p1[e] = (__bf16)0.f; ha1.p2[e] = (__bf16)0.f; ha1.p3[e] = (__bf16)0.f;
    }
    cs[0] = cs[1] = cs[2] = cs[3] = 0.f;
    q = 0;
    // ---------------- decoder scan + fused dense ----------------
#pragma unroll 2
    for (int t = 0; t < 128; ++t) {
        f32x4 z[4];
#pragma unroll
        for (int g = 0; g < 4; ++g) {
            f32x4 zc = zx[g];
            zc = mfma6(ha0, dU3[g][0], zc);
            zc = mfma6(ha1, dU3[g][1], zc);
            z[g] = zc;
        }
#pragma unroll
        for (int r = 0; r < 4; ++r) {
            float ig = fast_sig(z[0][r]);
            float fg = fast_sig(z[1][r]);
            float gg = fmaxf(z[2][r], 0.f);
            float og = fast_sig(z[3][r]);
            cs[r] = fg * cs[r] + ig * gg;
            float hv = og * fmaxf(cs[r], 0.f);
            bf3 s = split3(hv);
            *(__bf16*)(hraw[q][0] + offw[r]) = s.a;
            *(__bf16*)(hraw[q][1] + offw[r]) = s.b;
            *(__bf16*)(hraw[q][2] + offw[r]) = s.c;
        }
        hbar();
        ha0.p1 = *(const bf16x8*)(hraw[q][0] + offr0);
        ha0.p2 = *(const bf16x8*)(hraw[q][1] + offr0);
        ha0.p3 = *(const bf16x8*)(hraw[q][2] + offr0);
        ha1.p1 = *(const bf16x8*)(hraw[q][0] + offr1);
        ha1.p2 = *(const bf16x8*)(hraw[q][1] + offr1);
        ha1.p3 = *(const bf16x8*)(hraw[q][2] + offr1);
        // fused dense: out[b][t][:] = h_t @ nW + nb
        if (wv < 2) {
            f32x4 oa = {ob, ob, ob, ob};
            oa = mfma3(ha0, DN3[0], oa);
            oa = mfma3(ha1, DN3[1], oa);
#pragma unroll
            for (int r = 0; r < 4; ++r)
                out[((size_t)(b0 + lq * 4 + r) * 128 + t) * 32 + wv * 16 + l16] = oa[r];
        }
        q ^= 1;
    }
}

extern "C" void kernel_launch(void* const* d_in, const int* in_sizes, int n_in,
                              void* d_out, int out_size, void* d_ws, size_t ws_size,
                              hipStream_t stream) {
    const float* x  = (const float*)d_in[0];
    const float* eW = (const float*)d_in[1];
    const float* eU = (const float*)d_in[2];
    const float* eb = (const float*)d_in[3];
    const float* dW = (const float*)d_in[4];
    const float* dU = (const float*)d_in[5];
    const float* db = (const float*)d_in[6];
    const float* nW = (const float*)d_in[7];
    const float* nb = (const float*)d_in[8];
    float* out = (float*)d_out;

    hipLaunchKernelGGL(lstm_ae_kernel, dim3(4096 / 16), dim3(256), 0, stream,
                       x, eW, eU, eb, dW, dU, db, nW, nb, out);
}